// Round 10
// baseline (396.943 us; speedup 1.0000x reference)
//
#include <hip/hip_runtime.h>
#include <hip/hip_bf16.h>

// Problem constants
#define D    1024
#define LD   64
#define NTR  8192
#define NT   8192
#define DY   128

#define SHIFT 40.0f

typedef __attribute__((ext_vector_type(8))) short bf16x8;      // generic 8x16-bit
typedef __attribute__((ext_vector_type(8))) _Float16 half8;    // fp16 MFMA operand
typedef __attribute__((ext_vector_type(4))) short short4_;
typedef __attribute__((ext_vector_type(4))) float f4;

static __device__ __forceinline__ short f2bf(float f) {
    __hip_bfloat16 h = __float2bfloat16(f);
    short s; __builtin_memcpy(&s, &h, 2); return s;
}
static __device__ __forceinline__ float bf2f(short s) {
    __hip_bfloat16 h; __builtin_memcpy(&h, &s, 2); return __bfloat162float(h);
}
static __device__ __forceinline__ short f2h(float f) {
    _Float16 h = (_Float16)f;
    short s; __builtin_memcpy(&s, &h, 2); return s;
}
static __device__ __forceinline__ float h2f(short s) {
    _Float16 h; __builtin_memcpy(&h, &s, 2); return (float)h;
}

// async global->LDS DMA, 16 B per lane: LDS dest = wave-uniform base + lane*16
static __device__ __forceinline__ void gload_lds16(const void* g, void* l) {
    __builtin_amdgcn_global_load_lds(
        (const __attribute__((address_space(1))) unsigned int*)g,
        (__attribute__((address_space(3))) unsigned int*)l,
        16, 0, 0);
}

// ---------------------------------------------------------------------------
// K0: A -> fragment-ordered bf16 hi/lo (done ONCE; R9 proved inlining this
// into proj costs more than the launch it saves).
// ---------------------------------------------------------------------------
__global__ __launch_bounds__(256) void a_prep(const float* __restrict__ A,
                                              short* __restrict__ Afh,
                                              short* __restrict__ Afl) {
    int idx = blockIdx.x * 256 + threadIdx.x;    // 65536 elems, grid 256
    float a = A[idx];
    int k = idx >> 6;
    int col = idx & 63;
    short hi = f2bf(a);
    short lo = f2bf(a - bf2f(hi));
    int o = ((k >> 6) * 8 + ((k >> 5) & 1) * 4 + ((k >> 3) & 3)) * 512
          + col * 8 + (k & 7);
    Afh[o] = hi;
    Afl[o] = lo;
}

// ---------------------------------------------------------------------------
// K1 (proj + vtile, 768 blocks) — EXACT R6 body (best measured).
//   blocks   0..255 : test projection, 32 rows each -> qt fp16 hi/lo
//   blocks 256..511 : train projection, 32 rows each -> ktr + muAp slot
//   blocks 512..767 : ytr transpose -> V tiles
// ---------------------------------------------------------------------------
__global__ __launch_bounds__(256) void proj_prep(const float* __restrict__ xt,
                                                 const float* __restrict__ xtr,
                                                 const short* __restrict__ Afh,
                                                 const short* __restrict__ Afl,
                                                 const float* __restrict__ ytr,
                                                 short* __restrict__ qt_hi,
                                                 short* __restrict__ qt_lo,
                                                 short* __restrict__ ktr,
                                                 float* __restrict__ muAp,
                                                 short* __restrict__ vtile) {
    __shared__ __align__(16) char smraw[32768];

    int tid = threadIdx.x;
    int b = blockIdx.x;

    if (b >= 512) {
        // ---- ytr transpose -> swizzled V tiles (bf16) ----
        float* tile = (float*)smraw;             // [64][66] = 16896 B
        int bz = b - 512;
        int t0 = (bz & 127) * 64;
        int d0 = (bz >> 7) * 64;
        int c = tid & 63;
        int r4 = tid >> 6;
        #pragma unroll
        for (int i = 0; i < 16; ++i) {
            int r = i * 4 + r4;
            tile[r * 66 + c] = ytr[(long)(t0 + r) * DY + d0 + c];
        }
        __syncthreads();
        #pragma unroll
        for (int i = 0; i < 16; ++i) {
            int r = i * 4 + r4;       // dy local
            int t = t0 + c;
            int dy = d0 + r;
            long idx = (long)(t >> 5) * 4096 + (long)dy * 32
                     + ((((t >> 3) & 3) ^ (dy & 3)) << 3) + (t & 7);
            vtile[idx] = f2bf(tile[c * 66 + r]);
        }
        return;
    }

    // ---- projection ----
    // LDS: xh/xl[dbuf][32 rows][128 shorts], 16B chunks swizzled c^(row&7)
    short (*xh)[32][128] = (short (*)[32][128])smraw;              // 16384 B
    short (*xl)[32][128] = (short (*)[32][128])(smraw + 16384);    // 16384 B

    int wave = tid >> 6;          // = ct (column tile)
    int lane = tid & 63;
    int quad = lane >> 4;
    int l16 = lane & 15;

    bool is_test = b < 256;
    int row0 = (is_test ? b : b - 256) * 32;
    const float* x = is_test ? xt : xtr;

    // conversion role: thread covers row crow, chunks cg0 and cg0+8
    int crow = tid >> 3;          // 0..31
    int cg0 = tid & 7;            // 0..7
    const float* xg = x + (long)(row0 + crow) * D + cg0 * 8;
    int sw0 = ((cg0)     ^ (crow & 7)) * 8;   // swizzled chunk offsets (shorts)
    int sw1 = ((cg0 + 8) ^ (crow & 7)) * 8;

    int col = wave * 16 + l16;
    const short* AfhL = Afh + quad * 512 + col * 8;
    const short* AflL = Afl + quad * 512 + col * 8;

    f4 acc[2][2];                 // [rt][s2] independent chains
    #pragma unroll
    for (int rt = 0; rt < 2; ++rt)
        #pragma unroll
        for (int s2 = 0; s2 < 2; ++s2)
            acc[rt][s2] = (f4){0.f, 0.f, 0.f, 0.f};

    // prologue: convert step 0 into buf 0
    {
        f4 v0 = *(const f4*)xg;
        f4 v1 = *(const f4*)(xg + 4);
        f4 v2 = *(const f4*)(xg + 64);
        f4 v3 = *(const f4*)(xg + 68);
        bf16x8 h0, l0, h1, l1;
        #pragma unroll
        for (int e = 0; e < 4; ++e) {
            h0[e]     = f2bf(v0[e]);  l0[e]     = f2bf(v0[e] - bf2f(h0[e]));
            h0[e + 4] = f2bf(v1[e]);  l0[e + 4] = f2bf(v1[e] - bf2f(h0[e + 4]));
            h1[e]     = f2bf(v2[e]);  l1[e]     = f2bf(v2[e] - bf2f(h1[e]));
            h1[e + 4] = f2bf(v3[e]);  l1[e + 4] = f2bf(v3[e] - bf2f(h1[e + 4]));
        }
        *(bf16x8*)&xh[0][crow][sw0] = h0;
        *(bf16x8*)&xl[0][crow][sw0] = l0;
        *(bf16x8*)&xh[0][crow][sw1] = h1;
        *(bf16x8*)&xl[0][crow][sw1] = l1;
    }
    __syncthreads();

    #pragma unroll 1
    for (int s = 0; s < 8; ++s) {
        int cur = s & 1;

        // issue next-step global loads early (latency hides under MFMAs)
        f4 nv0, nv1, nv2, nv3;
        if (s < 7) {
            const float* ng = xg + (s + 1) * 128;
            nv0 = *(const f4*)ng;
            nv1 = *(const f4*)(ng + 4);
            nv2 = *(const f4*)(ng + 64);
            nv3 = *(const f4*)(ng + 68);
        }

        #pragma unroll
        for (int s2 = 0; s2 < 2; ++s2) {
            int s2g = s * 2 + s2;

            // B-fragments (shared by both row-tiles): bf16 hi/lo, L2-hot
            bf16x8 bh0 = *(const bf16x8*)(AfhL + s2g * 4096);
            bf16x8 bh1 = *(const bf16x8*)(AfhL + s2g * 4096 + 2048);
            bf16x8 bl0 = *(const bf16x8*)(AflL + s2g * 4096);
            bf16x8 bl1 = *(const bf16x8*)(AflL + s2g * 4096 + 2048);

            int ch0 = s2 * 8 + quad;            // chunk of cols s2*64+quad*8
            int sx0 = ((ch0)     ^ (l16 & 7)) * 8;
            int sx1 = ((ch0 + 4) ^ (l16 & 7)) * 8;

            #pragma unroll
            for (int rt = 0; rt < 2; ++rt) {
                const short* xhr = &xh[cur][rt * 16 + l16][0];
                const short* xlr = &xl[cur][rt * 16 + l16][0];
                bf16x8 ah0 = *(const bf16x8*)(xhr + sx0);
                bf16x8 ah1 = *(const bf16x8*)(xhr + sx1);
                bf16x8 al0 = *(const bf16x8*)(xlr + sx0);
                bf16x8 al1 = *(const bf16x8*)(xlr + sx1);

                acc[rt][s2] = __builtin_amdgcn_mfma_f32_16x16x32_bf16(ah0, bh0, acc[rt][s2], 0, 0, 0);
                acc[rt][s2] = __builtin_amdgcn_mfma_f32_16x16x32_bf16(al0, bh0, acc[rt][s2], 0, 0, 0);
                acc[rt][s2] = __builtin_amdgcn_mfma_f32_16x16x32_bf16(ah0, bl0, acc[rt][s2], 0, 0, 0);
                acc[rt][s2] = __builtin_amdgcn_mfma_f32_16x16x32_bf16(ah1, bh1, acc[rt][s2], 0, 0, 0);
                acc[rt][s2] = __builtin_amdgcn_mfma_f32_16x16x32_bf16(al1, bh1, acc[rt][s2], 0, 0, 0);
                acc[rt][s2] = __builtin_amdgcn_mfma_f32_16x16x32_bf16(ah1, bl1, acc[rt][s2], 0, 0, 0);
            }
        }

        // convert next step into the other buffer (its last readers finished
        // before the previous barrier -> one barrier per step suffices)
        if (s < 7) {
            bf16x8 h0, l0, h1, l1;
            #pragma unroll
            for (int e = 0; e < 4; ++e) {
                h0[e]     = f2bf(nv0[e]);  l0[e]     = f2bf(nv0[e] - bf2f(h0[e]));
                h0[e + 4] = f2bf(nv1[e]);  l0[e + 4] = f2bf(nv1[e] - bf2f(h0[e + 4]));
                h1[e]     = f2bf(nv2[e]);  l1[e]     = f2bf(nv2[e] - bf2f(h1[e]));
                h1[e + 4] = f2bf(nv3[e]);  l1[e + 4] = f2bf(nv3[e] - bf2f(h1[e + 4]));
            }
            *(bf16x8*)&xh[cur ^ 1][crow][sw0] = h0;
            *(bf16x8*)&xl[cur ^ 1][crow][sw0] = l0;
            *(bf16x8*)&xh[cur ^ 1][crow][sw1] = h1;
            *(bf16x8*)&xl[cur ^ 1][crow][sw1] = l1;
        }
        __syncthreads();
    }

    // D layout: row = rt*16+quad*4+r (x-row), col = wave*16+l16.  fp16 out.
    #pragma unroll
    for (int rt = 0; rt < 2; ++rt) {
        f4 q4 = acc[rt][0] + acc[rt][1];
        #pragma unroll
        for (int r = 0; r < 4; ++r) {
            int grow = row0 + rt * 16 + quad * 4 + r;
            float qv = q4[r];
            if (is_test) {
                short hi = f2h(qv);
                qt_hi[(long)grow * LD + col] = hi;
                qt_lo[(long)grow * LD + col] = f2h(qv - h2f(hi));
            } else {
                int tl = grow & 31;
                long idx = (long)(grow >> 5) * 2048 + tl * 64
                         + ((((col >> 3) ^ (tl & 7))) << 3) + (col & 7);
                ktr[idx] = f2h(qv);
            }
        }
    }

    // muA partial (train only): per-block slot, NO atomics / NO zero-init
    if (!is_test) {
        f4 t4 = (acc[0][0] + acc[0][1]) + (acc[1][0] + acc[1][1]);
        float s = t4[0] + t4[1] + t4[2] + t4[3];
        s += __shfl_xor(s, 16);
        s += __shfl_xor(s, 32);
        if (quad == 0) muAp[(long)(b - 256) * 64 + col] = s;
    }
}

// ---------------------------------------------------------------------------
// K2: cc[t] = muA . k_f16[t] + SHIFT — EXACT R6 body (R9 proved fusing this
// into flash costs ~10 us of redundant critical-path work).
// ---------------------------------------------------------------------------
__global__ __launch_bounds__(256) void c_kernel(const short* __restrict__ ktr,
                                                const float* __restrict__ muAp,
                                                float* __restrict__ cc) {
    __shared__ float red[4][64];
    __shared__ __align__(16) float muAs[64];
    int l = threadIdx.x & 63;
    int g = threadIdx.x >> 6;
    float ms = 0.f;
    #pragma unroll 8
    for (int p = g; p < 256; p += 4) ms += muAp[(long)p * 64 + l];
    red[g][l] = ms;
    __syncthreads();
    if (threadIdx.x < 64)
        muAs[l] = (red[0][l] + red[1][l] + red[2][l] + red[3][l]) *
                  (1.0f / (float)NTR);
    __syncthreads();

    int t = blockIdx.x * 256 + threadIdx.x;
    int tl = t & 31;
    long rb = (long)(t >> 5) * 2048 + tl * 64;
    float s = SHIFT;
    #pragma unroll
    for (int c = 0; c < 8; ++c) {
        int pos = (c ^ (tl & 7)) << 3;
        bf16x8 h8 = *(const bf16x8*)&ktr[rb + pos];   // fp16 bits
        f4 m0 = *(const f4*)&muAs[c * 8];
        f4 m1 = *(const f4*)&muAs[c * 8 + 4];
        #pragma unroll
        for (int j = 0; j < 4; ++j) {
            s += h2f(h8[j]) * m0[j];
            s += h2f(h8[j + 4]) * m1[j];
        }
    }
    cc[t] = s;
}

// ---------------------------------------------------------------------------
// K3: flash attention — FROZEN R4/R6 inner loop + R10 last-block fused
// finalize.  Each block stores its Opart/Lpart slice, release-fences, and
// atomically bumps done[qi]; the 16th (last) block per qi acquire-fences and
// runs the finalize math for its 128-row slice (same per-output op order as
// the old finalize_kernel -> bit-identical).  No spin, no co-residency
// assumption, no redundant work — removes the separate finalize kernel's
// launch + 37 MB standalone pass.  done[] zeroed per replay by a capture-safe
// hipMemsetAsync.  Fencing per G16/m20: atomicAdd is device-scope;
// __threadfence() release before the add, acquire after observing last.
// ---------------------------------------------------------------------------
template<int NC>
__global__ __launch_bounds__(256, 3) void flash_kernel(const short* __restrict__ qt_hi,
                                                       const short* __restrict__ qt_lo,
                                                       const short* __restrict__ ksw,
                                                       const short* __restrict__ vtile,
                                                       const float* __restrict__ cc,
                                                       short* __restrict__ Opart,
                                                       float* __restrict__ Lpart,
                                                       int* __restrict__ done,
                                                       float* __restrict__ out) {
    constexpr int TPC = 256 / NC;          // 32-row tiles per chunk
    constexpr int CH  = NTR / NC;          // train rows per chunk

    __shared__ __align__(16) short kbh[2][2048];    //  8 KB  K fp16 tiles
    __shared__ __align__(16) short vbuf[2][4096];   // 16 KB  V bf16 tiles
    __shared__ __align__(16) short ptile[4][1280];  // 10 KB  per-wave P[32][32] pitch 40
    __shared__ int lastflag;

    int tid = threadIdx.x;
    int wave = tid >> 6;
    int lane = tid & 63;
    int quad = lane >> 4;
    int l16 = lane & 15;

    int kc = blockIdx.x & (NC - 1);        // low bits -> XCD-affine chunk
    int qi = blockIdx.x / NC;
    int q0w = qi * 128 + wave * 32;
    int tile0 = kc * TPC;
    int kc0 = kc * CH;

    int soff = wave * 512 + lane * 8;     // staging src offset (shorts)
    int ldso = wave * 512;                // staging LDS base (wave-uniform)

    // Q fragments, fp16 hi/lo (B-operand for S^T)
    half8 qh[2][2], ql[2][2];
    #pragma unroll
    for (int rt = 0; rt < 2; ++rt) {
        const short* qrh = qt_hi + (long)(q0w + rt * 16 + l16) * LD + quad * 8;
        const short* qrl = qt_lo + (long)(q0w + rt * 16 + l16) * LD + quad * 8;
        qh[rt][0] = *(const half8*)qrh;
        qh[rt][1] = *(const half8*)(qrh + 32);
        ql[rt][0] = *(const half8*)qrl;
        ql[rt][1] = *(const half8*)(qrl + 32);
    }

    bf16x8 onef;
    #pragma unroll
    for (int i = 0; i < 8; ++i) onef[i] = (short)0x3F80;   // bf16(1.0)

    f4 Ov[2][8];
    f4 Lv[2];
    #pragma unroll
    for (int rt = 0; rt < 2; ++rt) {
        Lv[rt] = (f4){0.f, 0.f, 0.f, 0.f};
        #pragma unroll
        for (int jt = 0; jt < 8; ++jt) Ov[rt][jt] = (f4){0.f, 0.f, 0.f, 0.f};
    }

    short* myp = &ptile[wave][0];
    const int p0 = ((quad ^ (l16 & 7)) << 3);          // K chunk pos; h2=1 -> ^32
    const int pv = ((quad ^ (l16 & 3)) << 3);          // V chunk pos

    gload_lds16(ksw + (long)tile0 * 2048 + soff, &kbh[0][ldso]);
    gload_lds16(vtile + (long)tile0 * 4096 + soff, &vbuf[0][ldso]);
    gload_lds16(vtile + (long)tile0 * 4096 + 2048 + soff, &vbuf[0][2048 + ldso]);
    __syncthreads();

    #pragma unroll 1
    for (int it = 0; it < TPC; ++it) {
        int cur = it & 1;

        f4 cv[2];
        #pragma unroll
        for (int tt = 0; tt < 2; ++tt)
            cv[tt] = *(const f4*)&cc[kc0 + it * 32 + tt * 16 + quad * 4];

        if (it < TPC - 1) {
            int nb = cur ^ 1;
            long tb = (long)(tile0 + it + 1);
            gload_lds16(ksw + tb * 2048 + soff, &kbh[nb][ldso]);
            gload_lds16(vtile + tb * 4096 + soff, &vbuf[nb][ldso]);
            gload_lds16(vtile + tb * 4096 + 2048 + soff, &vbuf[nb][2048 + ldso]);
        }

        half8 kh[2][2];                    // [tt][h2], fp16
        #pragma unroll
        for (int tt = 0; tt < 2; ++tt) {
            int rb = (tt * 16 + l16) * 64;
            kh[tt][0] = *(const half8*)&kbh[cur][rb + p0];
            kh[tt][1] = *(const half8*)&kbh[cur][rb + (p0 ^ 32)];
        }

        f4 s[2][2];
        #pragma unroll
        for (int rt = 0; rt < 2; ++rt) {
            #pragma unroll
            for (int tt = 0; tt < 2; ++tt) {
                f4 a = (f4){0.f, 0.f, 0.f, 0.f};
                a = __builtin_amdgcn_mfma_f32_16x16x32_f16(kh[tt][0], qh[rt][0], a, 0, 0, 0);
                a = __builtin_amdgcn_mfma_f32_16x16x32_f16(kh[tt][0], ql[rt][0], a, 0, 0, 0);
                a = __builtin_amdgcn_mfma_f32_16x16x32_f16(kh[tt][1], qh[rt][1], a, 0, 0, 0);
                a = __builtin_amdgcn_mfma_f32_16x16x32_f16(kh[tt][1], ql[rt][1], a, 0, 0, 0);
                s[rt][tt] = a;
            }
        }

        #pragma unroll
        for (int rt = 0; rt < 2; ++rt) {
            #pragma unroll
            for (int tt = 0; tt < 2; ++tt) {
                short4_ p4;
                p4[0] = f2bf(__expf(s[rt][tt][0] - cv[tt][0]));
                p4[1] = f2bf(__expf(s[rt][tt][1] - cv[tt][1]));
                p4[2] = f2bf(__expf(s[rt][tt][2] - cv[tt][2]));
                p4[3] = f2bf(__expf(s[rt][tt][3] - cv[tt][3]));
                *(short4_*)&myp[(rt * 16 + l16) * 40 + tt * 16 + quad * 4] = p4;
            }
        }

        bf16x8 vf[8];
        #pragma unroll
        for (int jt = 0; jt < 8; ++jt)
            vf[jt] = *(const bf16x8*)&vbuf[cur][(jt * 16 + l16) * 32 + pv];
        #pragma unroll
        for (int rt = 0; rt < 2; ++rt) {
            bf16x8 pf = *(const bf16x8*)&myp[(rt * 16 + l16) * 40 + quad * 8];
            #pragma unroll
            for (int jt = 0; jt < 8; ++jt)
                Ov[rt][jt] = __builtin_amdgcn_mfma_f32_16x16x32_bf16(pf, vf[jt], Ov[rt][jt], 0, 0, 0);
            Lv[rt] = __builtin_amdgcn_mfma_f32_16x16x32_bf16(pf, onef, Lv[rt], 0, 0, 0);
        }

        __syncthreads();
    }

    long ob = (long)kc * NT;
    #pragma unroll
    for (int rt = 0; rt < 2; ++rt) {
        #pragma unroll
        for (int jt = 0; jt < 8; ++jt) {
            #pragma unroll
            for (int r = 0; r < 4; ++r)
                Opart[(ob + q0w + rt * 16 + quad * 4 + r) * DY + jt * 16 + l16] =
                    f2bf(Ov[rt][jt][r]);
        }
        if (l16 == 0) {
            #pragma unroll
            for (int r = 0; r < 4; ++r)
                Lpart[ob + q0w + rt * 16 + quad * 4 + r] = Lv[rt][r];
        }
    }

    // ---- R10 fused finalize: last kc-block per qi reduces its slice ----
    __threadfence();              // release: my Opart/Lpart visible device-wide
    __syncthreads();              // all threads in block have fenced
    if (tid == 0)
        lastflag = (atomicAdd(&done[qi], 1) == NC - 1);
    __syncthreads();
    if (lastflag) {
        __threadfence();          // acquire: drop stale cached copies
        #pragma unroll 1
        for (int u = 0; u < 8; ++u) {
            int idx = u * 256 + tid;              // 0..2047 -> (row, 8-chunk)
            long row = (long)qi * 128 + (idx >> 4);
            long i = row * DY + (idx & 15) * 8;
            float L = 0.f;
            f4 a = (f4){0.f, 0.f, 0.f, 0.f};
            f4 b2 = (f4){0.f, 0.f, 0.f, 0.f};
            #pragma unroll
            for (int k2 = 0; k2 < NC; ++k2) {
                L += Lpart[(long)k2 * NT + row];
                bf16x8 o = *(const bf16x8*)&Opart[(long)k2 * NT * DY + i];
                #pragma unroll
                for (int j = 0; j < 4; ++j) {
                    a[j]  += bf2f(o[j]);
                    b2[j] += bf2f(o[j + 4]);
                }
            }
            float linv = 1.0f / L;
            a *= linv; b2 *= linv;
            *(f4*)&out[i] = a;
            *(f4*)&out[i + 4] = b2;
        }
    }
}

// ---------------------------------------------------------------------------
extern "C" void kernel_launch(void* const* d_in, const int* in_sizes, int n_in,
                              void* d_out, int out_size, void* d_ws, size_t ws_size,
                              hipStream_t stream) {
    const float* xtr = (const float*)d_in[0];   // [NTR, D]
    const float* ytr = (const float*)d_in[1];   // [NTR, DY]
    const float* xt  = (const float*)d_in[2];   // [NT, D]
    const float* A   = (const float*)d_in[3];   // [D, LD]
    float* out = (float*)d_out;                 // [NT, DY]

    // NC=16 needs ~39.8 MB workspace; fall back to NC=8 if smaller.
    const size_t need16 =
        512 + (size_t)512 * 64 * 4 + (size_t)NTR * 4 +
        (size_t)16 * NT * 4 + (size_t)16 * NT * DY * 2 +
        (size_t)NT * LD * 2 * 2 + (size_t)NTR * LD * 2 +
        (size_t)DY * NTR * 2 + (size_t)D * LD * 2 * 2;
    const int NC = (ws_size >= need16) ? 16 : 8;

    // workspace carving (muAp fully written; done[] zeroed per replay below)
    char* w = (char*)d_ws;
    int*   done  = (int*)w;   w += 512;                           // 64 used
    float* muAp  = (float*)w; w += (size_t)512 * 64 * 4;          // 128 KB (256 used)
    float* cc    = (float*)w; w += (size_t)NTR * 4;               // 32 KB
    float* Lpart = (float*)w; w += (size_t)NC * NT * 4;
    short* Opart = (short*)w; w += (size_t)NC * NT * DY * 2;      // 16/32 MB (bf16)
    short* qt_hi  = (short*)w; w += (size_t)NT * LD * 2;          // 1 MB each (fp16)
    short* qt_lo  = (short*)w; w += (size_t)NT * LD * 2;
    short* ksw    = (short*)w; w += (size_t)NTR * LD * 2;         // fp16 swizzled tiles
    short* vtile  = (short*)w; w += (size_t)DY * NTR * 2;         // 2 MB bf16 swizzled
    short* Afh    = (short*)w; w += (size_t)D * LD * 2;           // 128 KB A hi frags
    short* Afl    = (short*)w; w += (size_t)D * LD * 2;           // 128 KB A lo frags
    (void)in_sizes; (void)n_in; (void)out_size;

    hipMemsetAsync(done, 0, 64 * sizeof(int), stream);   // capture-safe
    a_prep<<<256, 256, 0, stream>>>(A, Afh, Afl);
    proj_prep<<<768, 256, 0, stream>>>(xt, xtr, Afh, Afl, ytr,
                                       qt_hi, qt_lo, ksw, muAp, vtile);
    c_kernel<<<32, 256, 0, stream>>>(ksw, muAp, cc);
    if (NC == 16) {
        flash_kernel<16><<<64 * 16, 256, 0, stream>>>(qt_hi, qt_lo, ksw, vtile,
                                                      cc, Opart, Lpart, done, out);
    } else {
        flash_kernel<8><<<64 * 8, 256, 0, stream>>>(qt_hi, qt_lo, ksw, vtile,
                                                    cc, Opart, Lpart, done, out);
    }
}

// Round 11
// 162.616 us; speedup vs baseline: 2.4410x; 2.4410x over previous
//
#include <hip/hip_runtime.h>
#include <hip/hip_bf16.h>

// Problem constants
#define D    1024
#define LD   64
#define NTR  8192
#define NT   8192
#define DY   128

#define SHIFT 40.0f

typedef __attribute__((ext_vector_type(8))) short bf16x8;      // generic 8x16-bit
typedef __attribute__((ext_vector_type(8))) _Float16 half8;    // fp16 MFMA operand
typedef __attribute__((ext_vector_type(4))) short short4_;
typedef __attribute__((ext_vector_type(4))) float f4;

static __device__ __forceinline__ short f2bf(float f) {
    __hip_bfloat16 h = __float2bfloat16(f);
    short s; __builtin_memcpy(&s, &h, 2); return s;
}
static __device__ __forceinline__ float bf2f(short s) {
    __hip_bfloat16 h; __builtin_memcpy(&h, &s, 2); return __bfloat162float(h);
}
static __device__ __forceinline__ short f2h(float f) {
    _Float16 h = (_Float16)f;
    short s; __builtin_memcpy(&s, &h, 2); return s;
}
static __device__ __forceinline__ float h2f(short s) {
    _Float16 h; __builtin_memcpy(&h, &s, 2); return (float)h;
}

// async global->LDS DMA, 16 B per lane: LDS dest = wave-uniform base + lane*16
static __device__ __forceinline__ void gload_lds16(const void* g, void* l) {
    __builtin_amdgcn_global_load_lds(
        (const __attribute__((address_space(1))) unsigned int*)g,
        (__attribute__((address_space(3))) unsigned int*)l,
        16, 0, 0);
}

// ---------------------------------------------------------------------------
// R11 = exact R6 restoration (best measured: 161.6 us).  Session constraint
// map: flash inner loop frozen (R1/R3/R5 regress); kernel-boundary
// engineering dead on gfx950 (R8 grid.sync 431, R9 fusion 187, R10
// fence+atomic 397 — device-scope coherence ops cost tens of us across the
// 8 non-coherent XCD L2s); wins were all in-kernel work reduction
// (a_prep factoring, once-per-block x-conversion, 32-row proj + swizzle).
// ---------------------------------------------------------------------------

// ---------------------------------------------------------------------------
// K0: A -> fragment-ordered bf16 hi/lo (done ONCE, not per proj block).
// ---------------------------------------------------------------------------
__global__ __launch_bounds__(256) void a_prep(const float* __restrict__ A,
                                              short* __restrict__ Afh,
                                              short* __restrict__ Afl) {
    int idx = blockIdx.x * 256 + threadIdx.x;    // 65536 elems, grid 256
    float a = A[idx];
    int k = idx >> 6;
    int col = idx & 63;
    short hi = f2bf(a);
    short lo = f2bf(a - bf2f(hi));
    int o = ((k >> 6) * 8 + ((k >> 5) & 1) * 4 + ((k >> 3) & 3)) * 512
          + col * 8 + (k & 7);
    Afh[o] = hi;
    Afl[o] = lo;
}

// ---------------------------------------------------------------------------
// K1 (fused prep+proj, 768 blocks):
//   blocks   0..255 : test projection, 32 rows each -> qt fp16 hi/lo
//   blocks 256..511 : train projection, 32 rows each -> ktr + muAp slot
//   blocks 512..767 : ytr[NTR][DY] f32 -> V tiles [tile32][dy][32] bf16
// R6 proj: 32 rows/block (Af B-fragments amortized over 2 row-tiles),
// XOR-swizzled conflict-free LDS chunks, 4 independent acc chains.
// ---------------------------------------------------------------------------
__global__ __launch_bounds__(256) void proj_prep(const float* __restrict__ xt,
                                                 const float* __restrict__ xtr,
                                                 const short* __restrict__ Afh,
                                                 const short* __restrict__ Afl,
                                                 const float* __restrict__ ytr,
                                                 short* __restrict__ qt_hi,
                                                 short* __restrict__ qt_lo,
                                                 short* __restrict__ ktr,
                                                 float* __restrict__ muAp,
                                                 short* __restrict__ vtile) {
    __shared__ __align__(16) char smraw[32768];

    int tid = threadIdx.x;
    int b = blockIdx.x;

    if (b >= 512) {
        // ---- ytr transpose -> swizzled V tiles (bf16) ----
        float* tile = (float*)smraw;             // [64][66] = 16896 B
        int bz = b - 512;
        int t0 = (bz & 127) * 64;
        int d0 = (bz >> 7) * 64;
        int c = tid & 63;
        int r4 = tid >> 6;
        #pragma unroll
        for (int i = 0; i < 16; ++i) {
            int r = i * 4 + r4;
            tile[r * 66 + c] = ytr[(long)(t0 + r) * DY + d0 + c];
        }
        __syncthreads();
        #pragma unroll
        for (int i = 0; i < 16; ++i) {
            int r = i * 4 + r4;       // dy local
            int t = t0 + c;
            int dy = d0 + r;
            long idx = (long)(t >> 5) * 4096 + (long)dy * 32
                     + ((((t >> 3) & 3) ^ (dy & 3)) << 3) + (t & 7);
            vtile[idx] = f2bf(tile[c * 66 + r]);
        }
        return;
    }

    // ---- projection ----
    // LDS: xh/xl[dbuf][32 rows][128 shorts], 16B chunks swizzled c^(row&7)
    short (*xh)[32][128] = (short (*)[32][128])smraw;              // 16384 B
    short (*xl)[32][128] = (short (*)[32][128])(smraw + 16384);    // 16384 B

    int wave = tid >> 6;          // = ct (column tile)
    int lane = tid & 63;
    int quad = lane >> 4;
    int l16 = lane & 15;

    bool is_test = b < 256;
    int row0 = (is_test ? b : b - 256) * 32;
    const float* x = is_test ? xt : xtr;

    // conversion role: thread covers row crow, chunks cg0 and cg0+8
    int crow = tid >> 3;          // 0..31
    int cg0 = tid & 7;            // 0..7
    const float* xg = x + (long)(row0 + crow) * D + cg0 * 8;
    int sw0 = ((cg0)     ^ (crow & 7)) * 8;   // swizzled chunk offsets (shorts)
    int sw1 = ((cg0 + 8) ^ (crow & 7)) * 8;

    int col = wave * 16 + l16;
    const short* AfhL = Afh + quad * 512 + col * 8;
    const short* AflL = Afl + quad * 512 + col * 8;

    f4 acc[2][2];                 // [rt][s2] independent chains
    #pragma unroll
    for (int rt = 0; rt < 2; ++rt)
        #pragma unroll
        for (int s2 = 0; s2 < 2; ++s2)
            acc[rt][s2] = (f4){0.f, 0.f, 0.f, 0.f};

    // prologue: convert step 0 into buf 0
    {
        f4 v0 = *(const f4*)xg;
        f4 v1 = *(const f4*)(xg + 4);
        f4 v2 = *(const f4*)(xg + 64);
        f4 v3 = *(const f4*)(xg + 68);
        bf16x8 h0, l0, h1, l1;
        #pragma unroll
        for (int e = 0; e < 4; ++e) {
            h0[e]     = f2bf(v0[e]);  l0[e]     = f2bf(v0[e] - bf2f(h0[e]));
            h0[e + 4] = f2bf(v1[e]);  l0[e + 4] = f2bf(v1[e] - bf2f(h0[e + 4]));
            h1[e]     = f2bf(v2[e]);  l1[e]     = f2bf(v2[e] - bf2f(h1[e]));
            h1[e + 4] = f2bf(v3[e]);  l1[e + 4] = f2bf(v3[e] - bf2f(h1[e + 4]));
        }
        *(bf16x8*)&xh[0][crow][sw0] = h0;
        *(bf16x8*)&xl[0][crow][sw0] = l0;
        *(bf16x8*)&xh[0][crow][sw1] = h1;
        *(bf16x8*)&xl[0][crow][sw1] = l1;
    }
    __syncthreads();

    #pragma unroll 1
    for (int s = 0; s < 8; ++s) {
        int cur = s & 1;

        // issue next-step global loads early (latency hides under MFMAs)
        f4 nv0, nv1, nv2, nv3;
        if (s < 7) {
            const float* ng = xg + (s + 1) * 128;
            nv0 = *(const f4*)ng;
            nv1 = *(const f4*)(ng + 4);
            nv2 = *(const f4*)(ng + 64);
            nv3 = *(const f4*)(ng + 68);
        }

        #pragma unroll
        for (int s2 = 0; s2 < 2; ++s2) {
            int s2g = s * 2 + s2;

            // B-fragments (shared by both row-tiles): bf16 hi/lo, L2-hot
            bf16x8 bh0 = *(const bf16x8*)(AfhL + s2g * 4096);
            bf16x8 bh1 = *(const bf16x8*)(AfhL + s2g * 4096 + 2048);
            bf16x8 bl0 = *(const bf16x8*)(AflL + s2g * 4096);
            bf16x8 bl1 = *(const bf16x8*)(AflL + s2g * 4096 + 2048);

            int ch0 = s2 * 8 + quad;            // chunk of cols s2*64+quad*8
            int sx0 = ((ch0)     ^ (l16 & 7)) * 8;
            int sx1 = ((ch0 + 4) ^ (l16 & 7)) * 8;

            #pragma unroll
            for (int rt = 0; rt < 2; ++rt) {
                const short* xhr = &xh[cur][rt * 16 + l16][0];
                const short* xlr = &xl[cur][rt * 16 + l16][0];
                bf16x8 ah0 = *(const bf16x8*)(xhr + sx0);
                bf16x8 ah1 = *(const bf16x8*)(xhr + sx1);
                bf16x8 al0 = *(const bf16x8*)(xlr + sx0);
                bf16x8 al1 = *(const bf16x8*)(xlr + sx1);

                acc[rt][s2] = __builtin_amdgcn_mfma_f32_16x16x32_bf16(ah0, bh0, acc[rt][s2], 0, 0, 0);
                acc[rt][s2] = __builtin_amdgcn_mfma_f32_16x16x32_bf16(al0, bh0, acc[rt][s2], 0, 0, 0);
                acc[rt][s2] = __builtin_amdgcn_mfma_f32_16x16x32_bf16(ah0, bl0, acc[rt][s2], 0, 0, 0);
                acc[rt][s2] = __builtin_amdgcn_mfma_f32_16x16x32_bf16(ah1, bh1, acc[rt][s2], 0, 0, 0);
                acc[rt][s2] = __builtin_amdgcn_mfma_f32_16x16x32_bf16(al1, bh1, acc[rt][s2], 0, 0, 0);
                acc[rt][s2] = __builtin_amdgcn_mfma_f32_16x16x32_bf16(ah1, bl1, acc[rt][s2], 0, 0, 0);
            }
        }

        // convert next step into the other buffer (its last readers finished
        // before the previous barrier -> one barrier per step suffices)
        if (s < 7) {
            bf16x8 h0, l0, h1, l1;
            #pragma unroll
            for (int e = 0; e < 4; ++e) {
                h0[e]     = f2bf(nv0[e]);  l0[e]     = f2bf(nv0[e] - bf2f(h0[e]));
                h0[e + 4] = f2bf(nv1[e]);  l0[e + 4] = f2bf(nv1[e] - bf2f(h0[e + 4]));
                h1[e]     = f2bf(nv2[e]);  l1[e]     = f2bf(nv2[e] - bf2f(h1[e]));
                h1[e + 4] = f2bf(nv3[e]);  l1[e + 4] = f2bf(nv3[e] - bf2f(h1[e + 4]));
            }
            *(bf16x8*)&xh[cur ^ 1][crow][sw0] = h0;
            *(bf16x8*)&xl[cur ^ 1][crow][sw0] = l0;
            *(bf16x8*)&xh[cur ^ 1][crow][sw1] = h1;
            *(bf16x8*)&xl[cur ^ 1][crow][sw1] = l1;
        }
        __syncthreads();
    }

    // D layout: row = rt*16+quad*4+r (x-row), col = wave*16+l16.  fp16 out.
    #pragma unroll
    for (int rt = 0; rt < 2; ++rt) {
        f4 q4 = acc[rt][0] + acc[rt][1];
        #pragma unroll
        for (int r = 0; r < 4; ++r) {
            int grow = row0 + rt * 16 + quad * 4 + r;
            float qv = q4[r];
            if (is_test) {
                short hi = f2h(qv);
                qt_hi[(long)grow * LD + col] = hi;
                qt_lo[(long)grow * LD + col] = f2h(qv - h2f(hi));
            } else {
                int tl = grow & 31;
                long idx = (long)(grow >> 5) * 2048 + tl * 64
                         + ((((col >> 3) ^ (tl & 7))) << 3) + (col & 7);
                ktr[idx] = f2h(qv);
            }
        }
    }

    // muA partial (train only): per-block slot, NO atomics / NO zero-init
    if (!is_test) {
        f4 t4 = (acc[0][0] + acc[0][1]) + (acc[1][0] + acc[1][1]);
        float s = t4[0] + t4[1] + t4[2] + t4[3];
        s += __shfl_xor(s, 16);
        s += __shfl_xor(s, 32);
        if (quad == 0) muAp[(long)(b - 256) * 64 + col] = s;
    }
}

// ---------------------------------------------------------------------------
// K2: cc[t] = muA . k_f16[t] + SHIFT  (k_f16 = the fp16 K flash uses).
// muAp has 256 slots (32-row proj blocks).
// ---------------------------------------------------------------------------
__global__ __launch_bounds__(256) void c_kernel(const short* __restrict__ ktr,
                                                const float* __restrict__ muAp,
                                                float* __restrict__ cc) {
    __shared__ float red[4][64];
    __shared__ __align__(16) float muAs[64];
    int l = threadIdx.x & 63;
    int g = threadIdx.x >> 6;
    float ms = 0.f;
    #pragma unroll 8
    for (int p = g; p < 256; p += 4) ms += muAp[(long)p * 64 + l];
    red[g][l] = ms;
    __syncthreads();
    if (threadIdx.x < 64)
        muAs[l] = (red[0][l] + red[1][l] + red[2][l] + red[3][l]) *
                  (1.0f / (float)NTR);
    __syncthreads();

    int t = blockIdx.x * 256 + threadIdx.x;
    int tl = t & 31;
    long rb = (long)(t >> 5) * 2048 + tl * 64;
    float s = SHIFT;
    #pragma unroll
    for (int c = 0; c < 8; ++c) {
        int pos = (c ^ (tl & 7)) << 3;
        bf16x8 h8 = *(const bf16x8*)&ktr[rb + pos];   // fp16 bits
        f4 m0 = *(const f4*)&muAs[c * 8];
        f4 m1 = *(const f4*)&muAs[c * 8 + 4];
        #pragma unroll
        for (int j = 0; j < 4; ++j) {
            s += h2f(h8[j]) * m0[j];
            s += h2f(h8[j + 4]) * m1[j];
        }
    }
    cc[t] = s;
}

// ---------------------------------------------------------------------------
// K3: flash attention — FROZEN R4/R6 body (measured floor ~47.2 us):
// LDS-staged K/V via gload_lds, double-buffered, one __syncthreads per tile,
// NC=16 for 3 blocks/CU.  R1 (pipeline), R3 (direct-global K/V), R5
// (counted-vmcnt), R9 (fused c-prologue), R10 (fence+atomic finalize) all
// regressed; this structure is final.
// ---------------------------------------------------------------------------
template<int NC>
__global__ __launch_bounds__(256, 3) void flash_kernel(const short* __restrict__ qt_hi,
                                                       const short* __restrict__ qt_lo,
                                                       const short* __restrict__ ksw,
                                                       const short* __restrict__ vtile,
                                                       const float* __restrict__ cc,
                                                       short* __restrict__ Opart,
                                                       float* __restrict__ Lpart) {
    constexpr int TPC = 256 / NC;          // 32-row tiles per chunk
    constexpr int CH  = NTR / NC;          // train rows per chunk

    __shared__ __align__(16) short kbh[2][2048];    //  8 KB  K fp16 tiles
    __shared__ __align__(16) short vbuf[2][4096];   // 16 KB  V bf16 tiles
    __shared__ __align__(16) short ptile[4][1280];  // 10 KB  per-wave P[32][32] pitch 40

    int tid = threadIdx.x;
    int wave = tid >> 6;
    int lane = tid & 63;
    int quad = lane >> 4;
    int l16 = lane & 15;

    int kc = blockIdx.x & (NC - 1);        // low bits -> XCD-affine chunk
    int qi = blockIdx.x / NC;
    int q0w = qi * 128 + wave * 32;
    int tile0 = kc * TPC;
    int kc0 = kc * CH;

    int soff = wave * 512 + lane * 8;     // staging src offset (shorts)
    int ldso = wave * 512;                // staging LDS base (wave-uniform)

    // Q fragments, fp16 hi/lo (B-operand for S^T)
    half8 qh[2][2], ql[2][2];
    #pragma unroll
    for (int rt = 0; rt < 2; ++rt) {
        const short* qrh = qt_hi + (long)(q0w + rt * 16 + l16) * LD + quad * 8;
        const short* qrl = qt_lo + (long)(q0w + rt * 16 + l16) * LD + quad * 8;
        qh[rt][0] = *(const half8*)qrh;
        qh[rt][1] = *(const half8*)(qrh + 32);
        ql[rt][0] = *(const half8*)qrl;
        ql[rt][1] = *(const half8*)(qrl + 32);
    }

    bf16x8 onef;
    #pragma unroll
    for (int i = 0; i < 8; ++i) onef[i] = (short)0x3F80;   // bf16(1.0)

    f4 Ov[2][8];
    f4 Lv[2];
    #pragma unroll
    for (int rt = 0; rt < 2; ++rt) {
        Lv[rt] = (f4){0.f, 0.f, 0.f, 0.f};
        #pragma unroll
        for (int jt = 0; jt < 8; ++jt) Ov[rt][jt] = (f4){0.f, 0.f, 0.f, 0.f};
    }

    short* myp = &ptile[wave][0];
    const int p0 = ((quad ^ (l16 & 7)) << 3);          // K chunk pos; h2=1 -> ^32
    const int pv = ((quad ^ (l16 & 3)) << 3);          // V chunk pos

    gload_lds16(ksw + (long)tile0 * 2048 + soff, &kbh[0][ldso]);
    gload_lds16(vtile + (long)tile0 * 4096 + soff, &vbuf[0][ldso]);
    gload_lds16(vtile + (long)tile0 * 4096 + 2048 + soff, &vbuf[0][2048 + ldso]);
    __syncthreads();

    #pragma unroll 1
    for (int it = 0; it < TPC; ++it) {
        int cur = it & 1;

        f4 cv[2];
        #pragma unroll
        for (int tt = 0; tt < 2; ++tt)
            cv[tt] = *(const f4*)&cc[kc0 + it * 32 + tt * 16 + quad * 4];

        if (it < TPC - 1) {
            int nb = cur ^ 1;
            long tb = (long)(tile0 + it + 1);
            gload_lds16(ksw + tb * 2048 + soff, &kbh[nb][ldso]);
            gload_lds16(vtile + tb * 4096 + soff, &vbuf[nb][ldso]);
            gload_lds16(vtile + tb * 4096 + 2048 + soff, &vbuf[nb][2048 + ldso]);
        }

        half8 kh[2][2];                    // [tt][h2], fp16
        #pragma unroll
        for (int tt = 0; tt < 2; ++tt) {
            int rb = (tt * 16 + l16) * 64;
            kh[tt][0] = *(const half8*)&kbh[cur][rb + p0];
            kh[tt][1] = *(const half8*)&kbh[cur][rb + (p0 ^ 32)];
        }

        f4 s[2][2];
        #pragma unroll
        for (int rt = 0; rt < 2; ++rt) {
            #pragma unroll
            for (int tt = 0; tt < 2; ++tt) {
                f4 a = (f4){0.f, 0.f, 0.f, 0.f};
                a = __builtin_amdgcn_mfma_f32_16x16x32_f16(kh[tt][0], qh[rt][0], a, 0, 0, 0);
                a = __builtin_amdgcn_mfma_f32_16x16x32_f16(kh[tt][0], ql[rt][0], a, 0, 0, 0);
                a = __builtin_amdgcn_mfma_f32_16x16x32_f16(kh[tt][1], qh[rt][1], a, 0, 0, 0);
                a = __builtin_amdgcn_mfma_f32_16x16x32_f16(kh[tt][1], ql[rt][1], a, 0, 0, 0);
                s[rt][tt] = a;
            }
        }

        #pragma unroll
        for (int rt = 0; rt < 2; ++rt) {
            #pragma unroll
            for (int tt = 0; tt < 2; ++tt) {
                short4_ p4;
                p4[0] = f2bf(__expf(s[rt][tt][0] - cv[tt][0]));
                p4[1] = f2bf(__expf(s[rt][tt][1] - cv[tt][1]));
                p4[2] = f2bf(__expf(s[rt][tt][2] - cv[tt][2]));
                p4[3] = f2bf(__expf(s[rt][tt][3] - cv[tt][3]));
                *(short4_*)&myp[(rt * 16 + l16) * 40 + tt * 16 + quad * 4] = p4;
            }
        }

        bf16x8 vf[8];
        #pragma unroll
        for (int jt = 0; jt < 8; ++jt)
            vf[jt] = *(const bf16x8*)&vbuf[cur][(jt * 16 + l16) * 32 + pv];
        #pragma unroll
        for (int rt = 0; rt < 2; ++rt) {
            bf16x8 pf = *(const bf16x8*)&myp[(rt * 16 + l16) * 40 + quad * 8];
            #pragma unroll
            for (int jt = 0; jt < 8; ++jt)
                Ov[rt][jt] = __builtin_amdgcn_mfma_f32_16x16x32_bf16(pf, vf[jt], Ov[rt][jt], 0, 0, 0);
            Lv[rt] = __builtin_amdgcn_mfma_f32_16x16x32_bf16(pf, onef, Lv[rt], 0, 0, 0);
        }

        __syncthreads();
    }

    long ob = (long)kc * NT;
    #pragma unroll
    for (int rt = 0; rt < 2; ++rt) {
        #pragma unroll
        for (int jt = 0; jt < 8; ++jt) {
            #pragma unroll
            for (int r = 0; r < 4; ++r)
                Opart[(ob + q0w + rt * 16 + quad * 4 + r) * DY + jt * 16 + l16] =
                    f2bf(Ov[rt][jt][r]);
        }
        if (l16 == 0) {
            #pragma unroll
            for (int r = 0; r < 4; ++r)
                Lpart[ob + q0w + rt * 16 + quad * 4 + r] = Lv[rt][r];
        }
    }
}

// ---------------------------------------------------------------------------
// K4: out[q][dy] = sum_kc Opart[kc][q][dy] / sum_kc Lpart[kc][q]  (bf16 parts)
// ---------------------------------------------------------------------------
template<int NC>
__global__ __launch_bounds__(256) void finalize_kernel(const short* __restrict__ Opart,
                                                       const float* __restrict__ Lpart,
                                                       float* __restrict__ out) {
    long i = ((long)blockIdx.x * 256 + threadIdx.x) * 8;
    long row = i >> 7;          // DY = 128
    float L = 0.f;
    f4 a = (f4){0.f, 0.f, 0.f, 0.f};
    f4 b = (f4){0.f, 0.f, 0.f, 0.f};
    #pragma unroll
    for (int kc = 0; kc < NC; ++kc) {
        L += Lpart[(long)kc * NT + row];
        bf16x8 o = *(const bf16x8*)&Opart[(long)kc * NT * DY + i];
        #pragma unroll
        for (int j = 0; j < 4; ++j) {
            a[j] += bf2f(o[j]);
            b[j] += bf2f(o[j + 4]);
        }
    }
    float linv = 1.0f / L;
    a *= linv; b *= linv;
    *(f4*)&out[i] = a;
    *(f4*)&out[i + 4] = b;
}

// ---------------------------------------------------------------------------
extern "C" void kernel_launch(void* const* d_in, const int* in_sizes, int n_in,
                              void* d_out, int out_size, void* d_ws, size_t ws_size,
                              hipStream_t stream) {
    const float* xtr = (const float*)d_in[0];   // [NTR, D]
    const float* ytr = (const float*)d_in[1];   // [NTR, DY]
    const float* xt  = (const float*)d_in[2];   // [NT, D]
    const float* A   = (const float*)d_in[3];   // [D, LD]
    float* out = (float*)d_out;                 // [NT, DY]

    // NC=16 needs ~39.8 MB workspace; fall back to NC=8 if smaller.
    const size_t need16 =
        (size_t)512 * 64 * 4 + (size_t)NTR * 4 +
        (size_t)16 * NT * 4 + (size_t)16 * NT * DY * 2 +
        (size_t)NT * LD * 2 * 2 + (size_t)NTR * LD * 2 +
        (size_t)DY * NTR * 2 + (size_t)D * LD * 2 * 2;
    const int NC = (ws_size >= need16) ? 16 : 8;

    // workspace carving (no memset needed: muAp slots are fully written)
    char* w = (char*)d_ws;
    float* muAp  = (float*)w; w += (size_t)512 * 64 * 4;          // 128 KB (256 used)
    float* cc    = (float*)w; w += (size_t)NTR * 4;               // 32 KB
    float* Lpart = (float*)w; w += (size_t)NC * NT * 4;
    short* Opart = (short*)w; w += (size_t)NC * NT * DY * 2;      // 16/32 MB (bf16)
    short* qt_hi  = (short*)w; w += (size_t)NT * LD * 2;          // 1 MB each (fp16)
    short* qt_lo  = (short*)w; w += (size_t)NT * LD * 2;
    short* ksw    = (short*)w; w += (size_t)NTR * LD * 2;         // fp16 swizzled tiles
    short* vtile  = (short*)w; w += (size_t)DY * NTR * 2;         // 2 MB bf16 swizzled
    short* Afh    = (short*)w; w += (size_t)D * LD * 2;           // 128 KB A hi frags
    short* Afl    = (short*)w; w += (size_t)D * LD * 2;           // 128 KB A lo frags
    (void)in_sizes; (void)n_in; (void)out_size;

    a_prep<<<256, 256, 0, stream>>>(A, Afh, Afl);
    proj_prep<<<768, 256, 0, stream>>>(xt, xtr, Afh, Afl, ytr,
                                       qt_hi, qt_lo, ksw, muAp, vtile);
    c_kernel<<<32, 256, 0, stream>>>(ksw, muAp, cc);
    if (NC == 16) {
        flash_kernel<16><<<64 * 16, 256, 0, stream>>>(qt_hi, qt_lo, ksw, vtile,
                                                      cc, Opart, Lpart);
        finalize_kernel<16><<<(NT * DY) / (256 * 8), 256, 0, stream>>>(Opart,
                                                                       Lpart, out);
    } else {
        flash_kernel<8><<<64 * 8, 256, 0, stream>>>(qt_hi, qt_lo, ksw, vtile,
                                                    cc, Opart, Lpart);
        finalize_kernel<8><<<(NT * DY) / (256 * 8), 256, 0, stream>>>(Opart,
                                                                      Lpart, out);
    }
}

// Round 12
// 157.272 us; speedup vs baseline: 2.5239x; 1.0340x over previous
//
#include <hip/hip_runtime.h>
#include <hip/hip_bf16.h>

// Problem constants
#define D    1024
#define LD   64
#define NTR  8192
#define NT   8192
#define DY   128

#define SHIFT 40.0f

typedef __attribute__((ext_vector_type(8))) short bf16x8;      // generic 8x16-bit
typedef __attribute__((ext_vector_type(8))) _Float16 half8;    // fp16 MFMA operand
typedef __attribute__((ext_vector_type(4))) short short4_;
typedef __attribute__((ext_vector_type(4))) float f4;

static __device__ __forceinline__ short f2bf(float f) {
    __hip_bfloat16 h = __float2bfloat16(f);
    short s; __builtin_memcpy(&s, &h, 2); return s;
}
static __device__ __forceinline__ float bf2f(short s) {
    __hip_bfloat16 h; __builtin_memcpy(&h, &s, 2); return __bfloat162float(h);
}
static __device__ __forceinline__ short f2h(float f) {
    _Float16 h = (_Float16)f;
    short s; __builtin_memcpy(&s, &h, 2); return s;
}
static __device__ __forceinline__ float h2f(short s) {
    _Float16 h; __builtin_memcpy(&h, &s, 2); return (float)h;
}

// async global->LDS DMA, 16 B per lane: LDS dest = wave-uniform base + lane*16
static __device__ __forceinline__ void gload_lds16(const void* g, void* l) {
    __builtin_amdgcn_global_load_lds(
        (const __attribute__((address_space(1))) unsigned int*)g,
        (__attribute__((address_space(3))) unsigned int*)l,
        16, 0, 0);
}

// ---------------------------------------------------------------------------
// R12 = R11 (verified best, 162.6 us) + single-fp16 Q in flash QK.
// Rationale: logit error from K's fp16 quantization (~1.3e-3 std) is already
// accepted; adding Q's raises it only sqrt(2)x (~1.8e-3 -> 0.18% weight
// perturbation), far below the bf16-Opart storage floor (0.4%) that pins
// absmax at exactly 2^-5 across all 12 runs.  Drops 8 of 34 MFMAs/iter,
// halves the QK dependent chain, deletes qt_lo (proj store pass + 1 MB).
// Everything else is byte-identical to the verified R11 state.
// ---------------------------------------------------------------------------

// ---------------------------------------------------------------------------
// K0: A -> fragment-ordered bf16 hi/lo (done ONCE, not per proj block).
// ---------------------------------------------------------------------------
__global__ __launch_bounds__(256) void a_prep(const float* __restrict__ A,
                                              short* __restrict__ Afh,
                                              short* __restrict__ Afl) {
    int idx = blockIdx.x * 256 + threadIdx.x;    // 65536 elems, grid 256
    float a = A[idx];
    int k = idx >> 6;
    int col = idx & 63;
    short hi = f2bf(a);
    short lo = f2bf(a - bf2f(hi));
    int o = ((k >> 6) * 8 + ((k >> 5) & 1) * 4 + ((k >> 3) & 3)) * 512
          + col * 8 + (k & 7);
    Afh[o] = hi;
    Afl[o] = lo;
}

// ---------------------------------------------------------------------------
// K1 (fused prep+proj, 768 blocks):
//   blocks   0..255 : test projection, 32 rows each -> qt fp16 (single)
//   blocks 256..511 : train projection, 32 rows each -> ktr + muAp slot
//   blocks 512..767 : ytr[NTR][DY] f32 -> V tiles [tile32][dy][32] bf16
// R6 proj: 32 rows/block (Af B-fragments amortized over 2 row-tiles),
// XOR-swizzled conflict-free LDS chunks, 4 independent acc chains.
// ---------------------------------------------------------------------------
__global__ __launch_bounds__(256) void proj_prep(const float* __restrict__ xt,
                                                 const float* __restrict__ xtr,
                                                 const short* __restrict__ Afh,
                                                 const short* __restrict__ Afl,
                                                 const float* __restrict__ ytr,
                                                 short* __restrict__ qt_hi,
                                                 short* __restrict__ ktr,
                                                 float* __restrict__ muAp,
                                                 short* __restrict__ vtile) {
    __shared__ __align__(16) char smraw[32768];

    int tid = threadIdx.x;
    int b = blockIdx.x;

    if (b >= 512) {
        // ---- ytr transpose -> swizzled V tiles (bf16) ----
        float* tile = (float*)smraw;             // [64][66] = 16896 B
        int bz = b - 512;
        int t0 = (bz & 127) * 64;
        int d0 = (bz >> 7) * 64;
        int c = tid & 63;
        int r4 = tid >> 6;
        #pragma unroll
        for (int i = 0; i < 16; ++i) {
            int r = i * 4 + r4;
            tile[r * 66 + c] = ytr[(long)(t0 + r) * DY + d0 + c];
        }
        __syncthreads();
        #pragma unroll
        for (int i = 0; i < 16; ++i) {
            int r = i * 4 + r4;       // dy local
            int t = t0 + c;
            int dy = d0 + r;
            long idx = (long)(t >> 5) * 4096 + (long)dy * 32
                     + ((((t >> 3) & 3) ^ (dy & 3)) << 3) + (t & 7);
            vtile[idx] = f2bf(tile[c * 66 + r]);
        }
        return;
    }

    // ---- projection ----
    // LDS: xh/xl[dbuf][32 rows][128 shorts], 16B chunks swizzled c^(row&7)
    short (*xh)[32][128] = (short (*)[32][128])smraw;              // 16384 B
    short (*xl)[32][128] = (short (*)[32][128])(smraw + 16384);    // 16384 B

    int wave = tid >> 6;          // = ct (column tile)
    int lane = tid & 63;
    int quad = lane >> 4;
    int l16 = lane & 15;

    bool is_test = b < 256;
    int row0 = (is_test ? b : b - 256) * 32;
    const float* x = is_test ? xt : xtr;

    // conversion role: thread covers row crow, chunks cg0 and cg0+8
    int crow = tid >> 3;          // 0..31
    int cg0 = tid & 7;            // 0..7
    const float* xg = x + (long)(row0 + crow) * D + cg0 * 8;
    int sw0 = ((cg0)     ^ (crow & 7)) * 8;   // swizzled chunk offsets (shorts)
    int sw1 = ((cg0 + 8) ^ (crow & 7)) * 8;

    int col = wave * 16 + l16;
    const short* AfhL = Afh + quad * 512 + col * 8;
    const short* AflL = Afl + quad * 512 + col * 8;

    f4 acc[2][2];                 // [rt][s2] independent chains
    #pragma unroll
    for (int rt = 0; rt < 2; ++rt)
        #pragma unroll
        for (int s2 = 0; s2 < 2; ++s2)
            acc[rt][s2] = (f4){0.f, 0.f, 0.f, 0.f};

    // prologue: convert step 0 into buf 0
    {
        f4 v0 = *(const f4*)xg;
        f4 v1 = *(const f4*)(xg + 4);
        f4 v2 = *(const f4*)(xg + 64);
        f4 v3 = *(const f4*)(xg + 68);
        bf16x8 h0, l0, h1, l1;
        #pragma unroll
        for (int e = 0; e < 4; ++e) {
            h0[e]     = f2bf(v0[e]);  l0[e]     = f2bf(v0[e] - bf2f(h0[e]));
            h0[e + 4] = f2bf(v1[e]);  l0[e + 4] = f2bf(v1[e] - bf2f(h0[e + 4]));
            h1[e]     = f2bf(v2[e]);  l1[e]     = f2bf(v2[e] - bf2f(h1[e]));
            h1[e + 4] = f2bf(v3[e]);  l1[e + 4] = f2bf(v3[e] - bf2f(h1[e + 4]));
        }
        *(bf16x8*)&xh[0][crow][sw0] = h0;
        *(bf16x8*)&xl[0][crow][sw0] = l0;
        *(bf16x8*)&xh[0][crow][sw1] = h1;
        *(bf16x8*)&xl[0][crow][sw1] = l1;
    }
    __syncthreads();

    #pragma unroll 1
    for (int s = 0; s < 8; ++s) {
        int cur = s & 1;

        // issue next-step global loads early (latency hides under MFMAs)
        f4 nv0, nv1, nv2, nv3;
        if (s < 7) {
            const float* ng = xg + (s + 1) * 128;
            nv0 = *(const f4*)ng;
            nv1 = *(const f4*)(ng + 4);
            nv2 = *(const f4*)(ng + 64);
            nv3 = *(const f4*)(ng + 68);
        }

        #pragma unroll
        for (int s2 = 0; s2 < 2; ++s2) {
            int s2g = s * 2 + s2;

            // B-fragments (shared by both row-tiles): bf16 hi/lo, L2-hot
            bf16x8 bh0 = *(const bf16x8*)(AfhL + s2g * 4096);
            bf16x8 bh1 = *(const bf16x8*)(AfhL + s2g * 4096 + 2048);
            bf16x8 bl0 = *(const bf16x8*)(AflL + s2g * 4096);
            bf16x8 bl1 = *(const bf16x8*)(AflL + s2g * 4096 + 2048);

            int ch0 = s2 * 8 + quad;            // chunk of cols s2*64+quad*8
            int sx0 = ((ch0)     ^ (l16 & 7)) * 8;
            int sx1 = ((ch0 + 4) ^ (l16 & 7)) * 8;

            #pragma unroll
            for (int rt = 0; rt < 2; ++rt) {
                const short* xhr = &xh[cur][rt * 16 + l16][0];
                const short* xlr = &xl[cur][rt * 16 + l16][0];
                bf16x8 ah0 = *(const bf16x8*)(xhr + sx0);
                bf16x8 ah1 = *(const bf16x8*)(xhr + sx1);
                bf16x8 al0 = *(const bf16x8*)(xlr + sx0);
                bf16x8 al1 = *(const bf16x8*)(xlr + sx1);

                acc[rt][s2] = __builtin_amdgcn_mfma_f32_16x16x32_bf16(ah0, bh0, acc[rt][s2], 0, 0, 0);
                acc[rt][s2] = __builtin_amdgcn_mfma_f32_16x16x32_bf16(al0, bh0, acc[rt][s2], 0, 0, 0);
                acc[rt][s2] = __builtin_amdgcn_mfma_f32_16x16x32_bf16(ah0, bl0, acc[rt][s2], 0, 0, 0);
                acc[rt][s2] = __builtin_amdgcn_mfma_f32_16x16x32_bf16(ah1, bh1, acc[rt][s2], 0, 0, 0);
                acc[rt][s2] = __builtin_amdgcn_mfma_f32_16x16x32_bf16(al1, bh1, acc[rt][s2], 0, 0, 0);
                acc[rt][s2] = __builtin_amdgcn_mfma_f32_16x16x32_bf16(ah1, bl1, acc[rt][s2], 0, 0, 0);
            }
        }

        // convert next step into the other buffer (its last readers finished
        // before the previous barrier -> one barrier per step suffices)
        if (s < 7) {
            bf16x8 h0, l0, h1, l1;
            #pragma unroll
            for (int e = 0; e < 4; ++e) {
                h0[e]     = f2bf(nv0[e]);  l0[e]     = f2bf(nv0[e] - bf2f(h0[e]));
                h0[e + 4] = f2bf(nv1[e]);  l0[e + 4] = f2bf(nv1[e] - bf2f(h0[e + 4]));
                h1[e]     = f2bf(nv2[e]);  l1[e]     = f2bf(nv2[e] - bf2f(h1[e]));
                h1[e + 4] = f2bf(nv3[e]);  l1[e + 4] = f2bf(nv3[e] - bf2f(h1[e + 4]));
            }
            *(bf16x8*)&xh[cur ^ 1][crow][sw0] = h0;
            *(bf16x8*)&xl[cur ^ 1][crow][sw0] = l0;
            *(bf16x8*)&xh[cur ^ 1][crow][sw1] = h1;
            *(bf16x8*)&xl[cur ^ 1][crow][sw1] = l1;
        }
        __syncthreads();
    }

    // D layout: row = rt*16+quad*4+r (x-row), col = wave*16+l16.  fp16 out.
    #pragma unroll
    for (int rt = 0; rt < 2; ++rt) {
        f4 q4 = acc[rt][0] + acc[rt][1];
        #pragma unroll
        for (int r = 0; r < 4; ++r) {
            int grow = row0 + rt * 16 + quad * 4 + r;
            float qv = q4[r];
            if (is_test) {
                qt_hi[(long)grow * LD + col] = f2h(qv);   // single fp16 (R12)
            } else {
                int tl = grow & 31;
                long idx = (long)(grow >> 5) * 2048 + tl * 64
                         + ((((col >> 3) ^ (tl & 7))) << 3) + (col & 7);
                ktr[idx] = f2h(qv);
            }
        }
    }

    // muA partial (train only): per-block slot, NO atomics / NO zero-init
    if (!is_test) {
        f4 t4 = (acc[0][0] + acc[0][1]) + (acc[1][0] + acc[1][1]);
        float s = t4[0] + t4[1] + t4[2] + t4[3];
        s += __shfl_xor(s, 16);
        s += __shfl_xor(s, 32);
        if (quad == 0) muAp[(long)(b - 256) * 64 + col] = s;
    }
}

// ---------------------------------------------------------------------------
// K2: cc[t] = muA . k_f16[t] + SHIFT  (k_f16 = the fp16 K flash uses).
// muAp has 256 slots (32-row proj blocks).
// ---------------------------------------------------------------------------
__global__ __launch_bounds__(256) void c_kernel(const short* __restrict__ ktr,
                                                const float* __restrict__ muAp,
                                                float* __restrict__ cc) {
    __shared__ float red[4][64];
    __shared__ __align__(16) float muAs[64];
    int l = threadIdx.x & 63;
    int g = threadIdx.x >> 6;
    float ms = 0.f;
    #pragma unroll 8
    for (int p = g; p < 256; p += 4) ms += muAp[(long)p * 64 + l];
    red[g][l] = ms;
    __syncthreads();
    if (threadIdx.x < 64)
        muAs[l] = (red[0][l] + red[1][l] + red[2][l] + red[3][l]) *
                  (1.0f / (float)NTR);
    __syncthreads();

    int t = blockIdx.x * 256 + threadIdx.x;
    int tl = t & 31;
    long rb = (long)(t >> 5) * 2048 + tl * 64;
    float s = SHIFT;
    #pragma unroll
    for (int c = 0; c < 8; ++c) {
        int pos = (c ^ (tl & 7)) << 3;
        bf16x8 h8 = *(const bf16x8*)&ktr[rb + pos];   // fp16 bits
        f4 m0 = *(const f4*)&muAs[c * 8];
        f4 m1 = *(const f4*)&muAs[c * 8 + 4];
        #pragma unroll
        for (int j = 0; j < 4; ++j) {
            s += h2f(h8[j]) * m0[j];
            s += h2f(h8[j + 4]) * m1[j];
        }
    }
    cc[t] = s;
}

// ---------------------------------------------------------------------------
// K3: flash attention — FROZEN R4/R6 schedule; R12 drops the Q_lo operand:
// QK is now 2 MFMAs per (rt,tt) instead of 4 (s = k_f16 . q_f16).  Schedule,
// staging, barriers, P/V path all byte-identical to the verified R11 state.
// ---------------------------------------------------------------------------
template<int NC>
__global__ __launch_bounds__(256, 3) void flash_kernel(const short* __restrict__ qt_hi,
                                                       const short* __restrict__ ksw,
                                                       const short* __restrict__ vtile,
                                                       const float* __restrict__ cc,
                                                       short* __restrict__ Opart,
                                                       float* __restrict__ Lpart) {
    constexpr int TPC = 256 / NC;          // 32-row tiles per chunk
    constexpr int CH  = NTR / NC;          // train rows per chunk

    __shared__ __align__(16) short kbh[2][2048];    //  8 KB  K fp16 tiles
    __shared__ __align__(16) short vbuf[2][4096];   // 16 KB  V bf16 tiles
    __shared__ __align__(16) short ptile[4][1280];  // 10 KB  per-wave P[32][32] pitch 40

    int tid = threadIdx.x;
    int wave = tid >> 6;
    int lane = tid & 63;
    int quad = lane >> 4;
    int l16 = lane & 15;

    int kc = blockIdx.x & (NC - 1);        // low bits -> XCD-affine chunk
    int qi = blockIdx.x / NC;
    int q0w = qi * 128 + wave * 32;
    int tile0 = kc * TPC;
    int kc0 = kc * CH;

    int soff = wave * 512 + lane * 8;     // staging src offset (shorts)
    int ldso = wave * 512;                // staging LDS base (wave-uniform)

    // Q fragments, single fp16 (B-operand for S^T)
    half8 qh[2][2];
    #pragma unroll
    for (int rt = 0; rt < 2; ++rt) {
        const short* qrh = qt_hi + (long)(q0w + rt * 16 + l16) * LD + quad * 8;
        qh[rt][0] = *(const half8*)qrh;
        qh[rt][1] = *(const half8*)(qrh + 32);
    }

    bf16x8 onef;
    #pragma unroll
    for (int i = 0; i < 8; ++i) onef[i] = (short)0x3F80;   // bf16(1.0)

    f4 Ov[2][8];
    f4 Lv[2];
    #pragma unroll
    for (int rt = 0; rt < 2; ++rt) {
        Lv[rt] = (f4){0.f, 0.f, 0.f, 0.f};
        #pragma unroll
        for (int jt = 0; jt < 8; ++jt) Ov[rt][jt] = (f4){0.f, 0.f, 0.f, 0.f};
    }

    short* myp = &ptile[wave][0];
    const int p0 = ((quad ^ (l16 & 7)) << 3);          // K chunk pos; h2=1 -> ^32
    const int pv = ((quad ^ (l16 & 3)) << 3);          // V chunk pos

    gload_lds16(ksw + (long)tile0 * 2048 + soff, &kbh[0][ldso]);
    gload_lds16(vtile + (long)tile0 * 4096 + soff, &vbuf[0][ldso]);
    gload_lds16(vtile + (long)tile0 * 4096 + 2048 + soff, &vbuf[0][2048 + ldso]);
    __syncthreads();

    #pragma unroll 1
    for (int it = 0; it < TPC; ++it) {
        int cur = it & 1;

        f4 cv[2];
        #pragma unroll
        for (int tt = 0; tt < 2; ++tt)
            cv[tt] = *(const f4*)&cc[kc0 + it * 32 + tt * 16 + quad * 4];

        if (it < TPC - 1) {
            int nb = cur ^ 1;
            long tb = (long)(tile0 + it + 1);
            gload_lds16(ksw + tb * 2048 + soff, &kbh[nb][ldso]);
            gload_lds16(vtile + tb * 4096 + soff, &vbuf[nb][ldso]);
            gload_lds16(vtile + tb * 4096 + 2048 + soff, &vbuf[nb][2048 + ldso]);
        }

        half8 kh[2][2];                    // [tt][h2], fp16
        #pragma unroll
        for (int tt = 0; tt < 2; ++tt) {
            int rb = (tt * 16 + l16) * 64;
            kh[tt][0] = *(const half8*)&kbh[cur][rb + p0];
            kh[tt][1] = *(const half8*)&kbh[cur][rb + (p0 ^ 32)];
        }

        f4 s[2][2];
        #pragma unroll
        for (int rt = 0; rt < 2; ++rt) {
            #pragma unroll
            for (int tt = 0; tt < 2; ++tt) {
                f4 a = (f4){0.f, 0.f, 0.f, 0.f};
                a = __builtin_amdgcn_mfma_f32_16x16x32_f16(kh[tt][0], qh[rt][0], a, 0, 0, 0);
                a = __builtin_amdgcn_mfma_f32_16x16x32_f16(kh[tt][1], qh[rt][1], a, 0, 0, 0);
                s[rt][tt] = a;
            }
        }

        #pragma unroll
        for (int rt = 0; rt < 2; ++rt) {
            #pragma unroll
            for (int tt = 0; tt < 2; ++tt) {
                short4_ p4;
                p4[0] = f2bf(__expf(s[rt][tt][0] - cv[tt][0]));
                p4[1] = f2bf(__expf(s[rt][tt][1] - cv[tt][1]));
                p4[2] = f2bf(__expf(s[rt][tt][2] - cv[tt][2]));
                p4[3] = f2bf(__expf(s[rt][tt][3] - cv[tt][3]));
                *(short4_*)&myp[(rt * 16 + l16) * 40 + tt * 16 + quad * 4] = p4;
            }
        }

        bf16x8 vf[8];
        #pragma unroll
        for (int jt = 0; jt < 8; ++jt)
            vf[jt] = *(const bf16x8*)&vbuf[cur][(jt * 16 + l16) * 32 + pv];
        #pragma unroll
        for (int rt = 0; rt < 2; ++rt) {
            bf16x8 pf = *(const bf16x8*)&myp[(rt * 16 + l16) * 40 + quad * 8];
            #pragma unroll
            for (int jt = 0; jt < 8; ++jt)
                Ov[rt][jt] = __builtin_amdgcn_mfma_f32_16x16x32_bf16(pf, vf[jt], Ov[rt][jt], 0, 0, 0);
            Lv[rt] = __builtin_amdgcn_mfma_f32_16x16x32_bf16(pf, onef, Lv[rt], 0, 0, 0);
        }

        __syncthreads();
    }

    long ob = (long)kc * NT;
    #pragma unroll
    for (int rt = 0; rt < 2; ++rt) {
        #pragma unroll
        for (int jt = 0; jt < 8; ++jt) {
            #pragma unroll
            for (int r = 0; r < 4; ++r)
                Opart[(ob + q0w + rt * 16 + quad * 4 + r) * DY + jt * 16 + l16] =
                    f2bf(Ov[rt][jt][r]);
        }
        if (l16 == 0) {
            #pragma unroll
            for (int r = 0; r < 4; ++r)
                Lpart[ob + q0w + rt * 16 + quad * 4 + r] = Lv[rt][r];
        }
    }
}

// ---------------------------------------------------------------------------
// K4: out[q][dy] = sum_kc Opart[kc][q][dy] / sum_kc Lpart[kc][q]  (bf16 parts)
// ---------------------------------------------------------------------------
template<int NC>
__global__ __launch_bounds__(256) void finalize_kernel(const short* __restrict__ Opart,
                                                       const float* __restrict__ Lpart,
                                                       float* __restrict__ out) {
    long i = ((long)blockIdx.x * 256 + threadIdx.x) * 8;
    long row = i >> 7;          // DY = 128
    float L = 0.f;
    f4 a = (f4){0.f, 0.f, 0.f, 0.f};
    f4 b = (f4){0.f, 0.f, 0.f, 0.f};
    #pragma unroll
    for (int kc = 0; kc < NC; ++kc) {
        L += Lpart[(long)kc * NT + row];
        bf16x8 o = *(const bf16x8*)&Opart[(long)kc * NT * DY + i];
        #pragma unroll
        for (int j = 0; j < 4; ++j) {
            a[j] += bf2f(o[j]);
            b[j] += bf2f(o[j + 4]);
        }
    }
    float linv = 1.0f / L;
    a *= linv; b *= linv;
    *(f4*)&out[i] = a;
    *(f4*)&out[i + 4] = b;
}

// ---------------------------------------------------------------------------
extern "C" void kernel_launch(void* const* d_in, const int* in_sizes, int n_in,
                              void* d_out, int out_size, void* d_ws, size_t ws_size,
                              hipStream_t stream) {
    const float* xtr = (const float*)d_in[0];   // [NTR, D]
    const float* ytr = (const float*)d_in[1];   // [NTR, DY]
    const float* xt  = (const float*)d_in[2];   // [NT, D]
    const float* A   = (const float*)d_in[3];   // [D, LD]
    float* out = (float*)d_out;                 // [NT, DY]

    // NC=16 needs ~39 MB workspace; fall back to NC=8 if smaller.
    const size_t need16 =
        (size_t)512 * 64 * 4 + (size_t)NTR * 4 +
        (size_t)16 * NT * 4 + (size_t)16 * NT * DY * 2 +
        (size_t)NT * LD * 2 + (size_t)NTR * LD * 2 +
        (size_t)DY * NTR * 2 + (size_t)D * LD * 2 * 2;
    const int NC = (ws_size >= need16) ? 16 : 8;

    // workspace carving (no memset needed: muAp slots are fully written)
    char* w = (char*)d_ws;
    float* muAp  = (float*)w; w += (size_t)512 * 64 * 4;          // 128 KB (256 used)
    float* cc    = (float*)w; w += (size_t)NTR * 4;               // 32 KB
    float* Lpart = (float*)w; w += (size_t)NC * NT * 4;
    short* Opart = (short*)w; w += (size_t)NC * NT * DY * 2;      // 16/32 MB (bf16)
    short* qt_hi  = (short*)w; w += (size_t)NT * LD * 2;          // 1 MB (fp16)
    short* ksw    = (short*)w; w += (size_t)NTR * LD * 2;         // fp16 swizzled tiles
    short* vtile  = (short*)w; w += (size_t)DY * NTR * 2;         // 2 MB bf16 swizzled
    short* Afh    = (short*)w; w += (size_t)D * LD * 2;           // 128 KB A hi frags
    short* Afl    = (short*)w; w += (size_t)D * LD * 2;           // 128 KB A lo frags
    (void)in_sizes; (void)n_in; (void)out_size;

    a_prep<<<256, 256, 0, stream>>>(A, Afh, Afl);
    proj_prep<<<768, 256, 0, stream>>>(xt, xtr, Afh, Afl, ytr,
                                       qt_hi, ksw, muAp, vtile);
    c_kernel<<<32, 256, 0, stream>>>(ksw, muAp, cc);
    if (NC == 16) {
        flash_kernel<16><<<64 * 16, 256, 0, stream>>>(qt_hi, ksw, vtile,
                                                      cc, Opart, Lpart);
        finalize_kernel<16><<<(NT * DY) / (256 * 8), 256, 0, stream>>>(Opart,
                                                                       Lpart, out);
    } else {
        flash_kernel<8><<<64 * 8, 256, 0, stream>>>(qt_hi, ksw, vtile,
                                                    cc, Opart, Lpart);
        finalize_kernel<8><<<(NT * DY) / (256 * 8), 256, 0, stream>>>(Opart,
                                                                      Lpart, out);
    }
}